// Round 11
// baseline (922.770 us; speedup 1.0000x reference)
//
#include <hip/hip_runtime.h>
#include <cstdint>

typedef unsigned short u16;
typedef __bf16 bf16x8 __attribute__((ext_vector_type(8)));
typedef float f32x4 __attribute__((ext_vector_type(4)));

#define M_TOT 8192      // B*S
#define D_IN  4096
#define Z_DIM 1024
#define D_OUT 4096
#define K_CAT 5120      // Z + D_IN

struct alignas(8) u16x4 { u16 x, y, z, w; };

__device__ __forceinline__ u16 to_bf16(float f) {
    union { float f; uint32_t u; } v; v.f = f;
    uint32_t u = v.u;
    // round-to-nearest-even
    uint32_t r = (u + 0x7FFFu + ((u >> 16) & 1u)) >> 16;
    return (u16)r;
}

// Fast tanh: 1 - 2/(e^{2x}+1) via v_exp_f32 + v_rcp_f32 (~6 instr vs the
// ~50-100-cycle libm tanhf). Abs error ~1e-6 << bf16 ulp; saturates
// correctly (x>>0: e=inf -> 1; x<<0: e=0 -> -1). ~59M calls/iter across
// prep_x/ln/heads made libm tanhf a 40-80us VALU term.
__device__ __forceinline__ float fast_tanh(float x) {
    const float e = __expf(2.0f * x);
    return 1.0f - 2.0f * __builtin_amdgcn_rcpf(e + 1.0f);
}

__device__ __forceinline__ void async_load16(const void* g, void* l) {
    __builtin_amdgcn_global_load_lds(
        (const __attribute__((address_space(1))) void*)g,
        (__attribute__((address_space(3))) void*)l,
        16, 0, 0);
}

#define BAR() do { asm volatile("" ::: "memory"); \
                   __builtin_amdgcn_s_barrier(); \
                   asm volatile("" ::: "memory"); } while (0)

// ---------------------------------------------------------------------------
// 256x256-tile 8-phase GEMM — rev-6 schedule, verified best (317us/48.5%/
// 0 conflicts on the final projection). Converged; do not perturb.
// ---------------------------------------------------------------------------

#define STAGE_A(buf, h, kt_) do { if ((kt_) < nt) {                            \
    const u16* g_ = Ag + (long long)(h) * hstep + ((long long)(kt_) << 6);     \
    async_load16(g_,      &lds16[(buf) * 32768 + (h) * 8192        + wave * 512]); \
    async_load16(g_ + 32, &lds16[(buf) * 32768 + (h) * 8192 + 4096 + wave * 512]); \
  } } while (0)

#define STAGE_B(buf, h, kt_) do { if ((kt_) < nt) {                            \
    const u16* g_ = Bg + (long long)(h) * hstep + ((long long)(kt_) << 6);     \
    async_load16(g_,      &lds16[16384 + (buf) * 32768 + (h) * 8192        + wave * 512]); \
    async_load16(g_ + 32, &lds16[16384 + (buf) * 32768 + (h) * 8192 + 4096 + wave * 512]); \
  } } while (0)

#define LOAD_AF(buf, mbase)                                                    \
    _Pragma("unroll")                                                          \
    for (int mi_ = 0; mi_ < 4; ++mi_) {                                        \
      _Pragma("unroll")                                                        \
      for (int ks_ = 0; ks_ < 2; ++ks_)                                        \
        af[mi_][ks_] = *(const bf16x8*)&lds16[(buf) * 32768 + a_rd             \
                                              + ks_ * 4096 + ((mbase) + mi_) * 512]; \
    }

#define LOAD_B(dst, buf, nbase)                                                \
    _Pragma("unroll")                                                          \
    for (int ni_ = 0; ni_ < 2; ++ni_) {                                        \
      _Pragma("unroll")                                                        \
      for (int ks_ = 0; ks_ < 2; ++ks_)                                        \
        dst[ni_][ks_] = *(const bf16x8*)&lds16[(buf) * 32768 + b_rd            \
                                               + ks_ * 4096 + ((nbase) + ni_) * 512]; \
    }

#define MMA_Q(bfx, mo, no) do {                                                \
    __builtin_amdgcn_s_setprio(1);                                             \
    _Pragma("unroll")                                                          \
    for (int mi_ = 0; mi_ < 4; ++mi_) {                                        \
      _Pragma("unroll")                                                        \
      for (int ni_ = 0; ni_ < 2; ++ni_) {                                      \
        _Pragma("unroll")                                                      \
        for (int ks_ = 0; ks_ < 2; ++ks_)                                      \
          acc[(mo) + mi_][(no) + ni_] = __builtin_amdgcn_mfma_f32_16x16x32_bf16( \
              af[mi_][ks_], bfx[ni_][ks_], acc[(mo) + mi_][(no) + ni_], 0, 0, 0); \
      }                                                                        \
    }                                                                          \
    __builtin_amdgcn_s_setprio(0);                                             \
  } while (0)

#define TILE(b, kt_) do {                                                      \
    LOAD_AF(b, 0);                                                             \
    STAGE_A((b) ^ 1, 0, (kt_) + 1);                                            \
    BAR();                                                                     \
    MMA_Q(bf0, 0, 0);                                                          \
    BAR();                                                                     \
    LOAD_B(bf1, b, 2);                                                         \
    STAGE_A((b) ^ 1, 1, (kt_) + 1);                                            \
    BAR();                                                                     \
    MMA_Q(bf1, 0, 2);                                                          \
    BAR();                                                                     \
    LOAD_AF(b, 4);                                                             \
    STAGE_B(b, 0, (kt_) + 2);                                                  \
    BAR();                                                                     \
    MMA_Q(bf0, 4, 0);                                                          \
    BAR();                                                                     \
    STAGE_B(b, 1, (kt_) + 2);                                                  \
    if ((kt_) + 2 < nt) { asm volatile("s_waitcnt vmcnt(4)" ::: "memory"); }   \
    else                { asm volatile("s_waitcnt vmcnt(0)" ::: "memory"); }   \
    BAR();                                                                     \
    LOAD_B(bf0, (b) ^ 1, 0);                                                   \
    MMA_Q(bf1, 4, 2);                                                          \
    BAR();                                                                     \
  } while (0)

__global__ __launch_bounds__(512)
void gemm256(const u16* __restrict__ A, const u16* __restrict__ Bw,
             const float* __restrict__ bias, float* __restrict__ C,
             int M, int N, int K)
{
    __shared__ u16 lds16[65536];          // 128 KiB

    const int tid  = threadIdx.x;
    const int wave = tid >> 6;
    const int lane = tid & 63;
    const int fr   = lane & 15;
    const int fq   = lane >> 4;
    const int wm   = (wave >> 2) * 128;   // 2 wave-rows (M)
    const int wn   = (wave & 3) * 64;     // 4 wave-cols (N)

    const int nwg  = (int)(gridDim.x * gridDim.y);
    const int bid0 = (int)(blockIdx.y * gridDim.x + blockIdx.x);
    const int bid  = (bid0 & 7) * (nwg >> 3) + (bid0 >> 3);
    const int n0   = (bid % (int)gridDim.x) * 256;
    const int m0   = (bid / (int)gridDim.x) * 256;

    const int nt = K >> 6;                // # K-tiles (BK=64); even by contract

    const int csrc = (tid & 3) ^ ((tid >> 4) & 2);
    const u16* Ag = A  + (long long)(m0 + (tid >> 2)) * K + csrc * 8;
    const u16* Bg = Bw + (long long)(n0 + (tid >> 2)) * K + csrc * 8;
    const long long hstep = 128LL * K;

    const int swz  = (fq * 8) ^ ((fr & 8) << 1);
    const int a_rd = (wave >> 2) * 8192 + fr * 32 + swz;
    const int b_rd = 16384 + ((wave & 3) >> 1) * 8192
                   + ((wave & 1) * 64 + fr) * 32 + swz;

    f32x4 acc[8][4] = {};
    bf16x8 af[4][2], bf0[2][2], bf1[2][2];

    STAGE_B(0, 0, 0);
    STAGE_B(0, 1, 0);
    STAGE_A(0, 0, 0);
    STAGE_A(0, 1, 0);
    STAGE_B(1, 0, 1);
    STAGE_B(1, 1, 1);
    asm volatile("s_waitcnt vmcnt(4)" ::: "memory");
    BAR();
    LOAD_B(bf0, 0, 0);

    #pragma unroll 1
    for (int kt = 0; kt < nt; kt += 2) {
        TILE(0, kt);
        TILE(1, kt + 1);
    }

    #pragma unroll
    for (int ni = 0; ni < 4; ++ni) {
        const int col = n0 + wn + ni * 16 + fr;
        const float bv = bias[col];
        #pragma unroll
        for (int mi = 0; mi < 8; ++mi) {
            const int row = m0 + wm + mi * 16 + fq * 4;
            float* cp = C + (long long)row * N + col;
            #pragma unroll
            for (int r = 0; r < 4; ++r)
                cp[(long long)r * N] = acc[mi][ni][r] + bv;
        }
    }
}

#undef STAGE_A
#undef STAGE_B
#undef LOAD_AF
#undef LOAD_B
#undef MMA_Q
#undef TILE

// ---------------------------------------------------------------------------
// 256x128-tile GEMM (gemm128n) — verified last round (877us total, −29).
// BM=256, BN=128, BK=64; 8 waves; LDS 96KB; 2 phases/K-tile; vmcnt(2).
// ---------------------------------------------------------------------------

#define STAGE_A1(buf, h, kt_) do { if ((kt_) < nt) {                           \
    const u16* g_ = Ag + (long long)(h) * hstep + ((long long)(kt_) << 6);     \
    async_load16(g_,      &lds16[(buf) * 24576 + (h) * 8192        + wave * 512]); \
    async_load16(g_ + 32, &lds16[(buf) * 24576 + (h) * 8192 + 4096 + wave * 512]); \
  } } while (0)

#define STAGE_B1(buf, kt_) do { if ((kt_) < nt) {                              \
    const u16* g_ = Bg + ((long long)(kt_) << 6);                              \
    async_load16(g_,      &lds16[(buf) * 24576 + 16384        + wave * 512]);  \
    async_load16(g_ + 32, &lds16[(buf) * 24576 + 16384 + 4096 + wave * 512]);  \
  } } while (0)

#define LOAD_AF1(buf, mbase)                                                   \
    _Pragma("unroll")                                                          \
    for (int mi_ = 0; mi_ < 4; ++mi_) {                                        \
      _Pragma("unroll")                                                        \
      for (int ks_ = 0; ks_ < 2; ++ks_)                                        \
        af[mi_][ks_] = *(const bf16x8*)&lds16[(buf) * 24576 + a_rd             \
                                              + ks_ * 4096 + ((mbase) + mi_) * 512]; \
    }

#define LOAD_BF1(dst, buf)                                                     \
    _Pragma("unroll")                                                          \
    for (int ni_ = 0; ni_ < 2; ++ni_) {                                        \
      _Pragma("unroll")                                                        \
      for (int ks_ = 0; ks_ < 2; ++ks_)                                        \
        dst[ni_][ks_] = *(const bf16x8*)&lds16[(buf) * 24576 + b_rd            \
                                               + ks_ * 4096 + ni_ * 512];      \
    }

#define MMA_H(bfx, mo) do {                                                    \
    __builtin_amdgcn_s_setprio(1);                                             \
    _Pragma("unroll")                                                          \
    for (int mi_ = 0; mi_ < 4; ++mi_) {                                        \
      _Pragma("unroll")                                                        \
      for (int ni_ = 0; ni_ < 2; ++ni_) {                                      \
        _Pragma("unroll")                                                      \
        for (int ks_ = 0; ks_ < 2; ++ks_)                                      \
          acc[(mo) + mi_][ni_] = __builtin_amdgcn_mfma_f32_16x16x32_bf16(      \
              af[mi_][ks_], bfx[ni_][ks_], acc[(mo) + mi_][ni_], 0, 0, 0);     \
      }                                                                        \
    }                                                                          \
    __builtin_amdgcn_s_setprio(0);                                             \
  } while (0)

#define TILE1(b, kt_, bfCur, bfNxt) do {                                       \
    LOAD_AF1(b, 0);                                                            \
    STAGE_A1((b) ^ 1, 0, (kt_) + 1);                                           \
    BAR();                                                                     \
    MMA_H(bfCur, 0);                                                           \
    BAR();                                                                     \
    LOAD_AF1(b, 4);                                                            \
    STAGE_A1((b) ^ 1, 1, (kt_) + 1);                                           \
    STAGE_B1(b, (kt_) + 2);                                                    \
    if ((kt_) + 2 < nt) { asm volatile("s_waitcnt vmcnt(2)" ::: "memory"); }   \
    else                { asm volatile("s_waitcnt vmcnt(0)" ::: "memory"); }   \
    BAR();                                                                     \
    LOAD_BF1(bfNxt, (b) ^ 1);                                                  \
    MMA_H(bfCur, 4);                                                           \
    BAR();                                                                     \
  } while (0)

__global__ __launch_bounds__(512)
void gemm128n(const u16* __restrict__ A, const u16* __restrict__ Bw,
              const float* __restrict__ bias, float* __restrict__ C,
              int M, int N, int K)
{
    __shared__ u16 lds16[49152];          // 96 KiB

    const int tid  = threadIdx.x;
    const int wave = tid >> 6;
    const int lane = tid & 63;
    const int fr   = lane & 15;
    const int fq   = lane >> 4;
    const int wm   = (wave >> 2) * 128;   // 2 wave-rows (M)
    const int wn   = (wave & 3) * 32;     // 4 wave-cols (N)

    const int nwg  = (int)(gridDim.x * gridDim.y);
    const int bid0 = (int)(blockIdx.y * gridDim.x + blockIdx.x);
    const int bid  = (bid0 & 7) * (nwg >> 3) + (bid0 >> 3);
    const int n0   = (bid % (int)gridDim.x) * 128;
    const int m0   = (bid / (int)gridDim.x) * 256;

    const int nt = K >> 6;                // even by contract (K%128==0)

    const int csrc = (tid & 3) ^ ((tid >> 4) & 2);
    const u16* Ag = A  + (long long)(m0 + (tid >> 2)) * K + csrc * 8;
    const u16* Bg = Bw + (long long)(n0 + (tid >> 2)) * K + csrc * 8;
    const long long hstep = 128LL * K;

    const int swz  = (fq * 8) ^ ((fr & 8) << 1);
    const int a_rd = (wave >> 2) * 8192 + fr * 32 + swz;
    const int b_rd = 16384 + ((wave & 3) * 32 + fr) * 32 + swz;

    f32x4 acc[8][2] = {};
    bf16x8 af[4][2], bfA[2][2], bfB[2][2];

    STAGE_B1(0, 0);
    STAGE_A1(0, 0, 0);
    STAGE_A1(0, 1, 0);
    STAGE_B1(1, 1);
    asm volatile("s_waitcnt vmcnt(2)" ::: "memory");
    BAR();
    LOAD_BF1(bfA, 0);

    #pragma unroll 1
    for (int kt = 0; kt < nt; kt += 2) {
        TILE1(0, kt,     bfA, bfB);
        TILE1(1, kt + 1, bfB, bfA);
    }

    #pragma unroll
    for (int ni = 0; ni < 2; ++ni) {
        const int col = n0 + wn + ni * 16 + fr;
        const float bv = bias[col];
        #pragma unroll
        for (int mi = 0; mi < 8; ++mi) {
            const int row = m0 + wm + mi * 16 + fq * 4;
            float* cp = C + (long long)row * N + col;
            #pragma unroll
            for (int r = 0; r < 4; ++r)
                cp[(long long)r * N] = acc[mi][ni][r] + bv;
        }
    }
}

#undef STAGE_A1
#undef STAGE_B1
#undef LOAD_AF1
#undef LOAD_BF1
#undef MMA_H
#undef TILE1

// ---------------------------------------------------------------------------
// Fused mu+logsigma heads GEMM + reparameterization (gemm_heads).
//   Each block computes BOTH heads for a 256x128 tile: shared A staging,
//   Bmu + Bls staged per K-tile; accMu/accLs = 64+64 regs; frag live-set
//   af(32V) + bfMu(16V) + bfLs(16V) = 64V — same budget class as gemm128n
//   (rev-4/5 spill lesson respected). Epilogue fuses the whole reparam:
//   mu (+bias) -> mu[], std = exp(0.5*(ls+bias)) -> std_[],
//   tanh(eps*std + mu) -> zc left half. Kills the reparam kernel + the
//   mu/std HBM round-trip (~67MB) + one launch.
//   Schedule = gemm128n's 2-phase skeleton; per K-tile stages {A-h0 | A-h1,
//   Bmu(t+2), Bls(t+2)}; at p1's wait outstanding = B(t+1)x4 (from t-1),
//   A(t+1)x4, B(t+2)x4 -> vmcnt(4) drains B(t+1)+A(t+1) exactly, keeps
//   B(t+2); barrier globalizes t+1 residency. bf reads are in-phase (p0),
//   consumed by p0+p1 MFMAs; B(t) LDS region free after p0's closing
//   barrier -> stage B(t+2) into it at p1. N == 1024 (Z_DIM) fixed.
//   Grid (8, 32) = 256 blocks = 1/CU. M%256==0, K%128==0.
// ---------------------------------------------------------------------------

#define STAGE_AH(buf, h, kt_) do { if ((kt_) < nt) {                           \
    const u16* g_ = Ag + (long long)(h) * hstep + ((long long)(kt_) << 6);     \
    async_load16(g_,      &lds16[(buf) * 32768 + (h) * 8192        + wave * 512]); \
    async_load16(g_ + 32, &lds16[(buf) * 32768 + (h) * 8192 + 4096 + wave * 512]); \
  } } while (0)

#define STAGE_BH(buf, bsel, kt_) do { if ((kt_) < nt) {                        \
    const u16* g_ = ((bsel) ? Blsg : Bmug) + ((long long)(kt_) << 6);          \
    async_load16(g_,      &lds16[(buf) * 32768 + 16384 + (bsel) * 8192        + wave * 512]); \
    async_load16(g_ + 32, &lds16[(buf) * 32768 + 16384 + (bsel) * 8192 + 4096 + wave * 512]); \
  } } while (0)

#define LOAD_AFH(buf, mbase)                                                   \
    _Pragma("unroll")                                                          \
    for (int mi_ = 0; mi_ < 4; ++mi_) {                                        \
      _Pragma("unroll")                                                        \
      for (int ks_ = 0; ks_ < 2; ++ks_)                                        \
        af[mi_][ks_] = *(const bf16x8*)&lds16[(buf) * 32768 + a_rd             \
                                              + ks_ * 4096 + ((mbase) + mi_) * 512]; \
    }

#define LOAD_BH(dst, buf, bsel)                                                \
    _Pragma("unroll")                                                          \
    for (int ni_ = 0; ni_ < 2; ++ni_) {                                        \
      _Pragma("unroll")                                                        \
      for (int ks_ = 0; ks_ < 2; ++ks_)                                        \
        dst[ni_][ks_] = *(const bf16x8*)&lds16[(buf) * 32768 + 16384           \
                + (bsel) * 8192 + bh_rd + ks_ * 4096 + ni_ * 512];             \
    }

#define MMA_H2(accX, bfx, mo) do {                                             \
    __builtin_amdgcn_s_setprio(1);                                             \
    _Pragma("unroll")                                                          \
    for (int mi_ = 0; mi_ < 4; ++mi_) {                                        \
      _Pragma("unroll")                                                        \
      for (int ni_ = 0; ni_ < 2; ++ni_) {                                      \
        _Pragma("unroll")                                                      \
        for (int ks_ = 0; ks_ < 2; ++ks_)                                      \
          accX[(mo) + mi_][ni_] = __builtin_amdgcn_mfma_f32_16x16x32_bf16(     \
              af[mi_][ks_], bfx[ni_][ks_], accX[(mo) + mi_][ni_], 0, 0, 0);    \
      }                                                                        \
    }                                                                          \
    __builtin_amdgcn_s_setprio(0);                                             \
  } while (0)

#define TILE_H(b, kt_) do {                                                    \
    /* p0: af-lo + both B heads; stage A-h0(t+1); MMA m-lo both heads */       \
    LOAD_AFH(b, 0);                                                            \
    LOAD_BH(bfMu, b, 0);                                                       \
    LOAD_BH(bfLs, b, 1);                                                       \
    STAGE_AH((b) ^ 1, 0, (kt_) + 1);                                           \
    BAR();                                                                     \
    MMA_H2(accMu, bfMu, 0);                                                    \
    MMA_H2(accLs, bfLs, 0);                                                    \
    BAR();                                                                     \
    /* p1: af-hi; stage A-h1(t+1) + Bmu/Bls(t+2); residency; MMA m-hi */       \
    LOAD_AFH(b, 4);                                                            \
    STAGE_AH((b) ^ 1, 1, (kt_) + 1);                                           \
    STAGE_BH(b, 0, (kt_) + 2);                                                 \
    STAGE_BH(b, 1, (kt_) + 2);                                                 \
    if ((kt_) + 2 < nt) { asm volatile("s_waitcnt vmcnt(4)" ::: "memory"); }   \
    else                { asm volatile("s_waitcnt vmcnt(0)" ::: "memory"); }   \
    BAR();                                                                     \
    MMA_H2(accMu, bfMu, 4);                                                    \
    MMA_H2(accLs, bfLs, 4);                                                    \
    BAR();                                                                     \
  } while (0)

__global__ __launch_bounds__(512)
void gemm_heads(const u16* __restrict__ A,
                const u16* __restrict__ Wmu, const u16* __restrict__ Wls,
                const float* __restrict__ bmu, const float* __restrict__ bls,
                const float* __restrict__ eps,
                float* __restrict__ muO, float* __restrict__ stdO,
                u16* __restrict__ zc, int K)
{
    __shared__ u16 lds16[65536];          // 128 KiB: 2 x (A 32K + Bmu 16K + Bls 16K)

    const int tid  = threadIdx.x;
    const int wave = tid >> 6;
    const int lane = tid & 63;
    const int fr   = lane & 15;
    const int fq   = lane >> 4;
    const int wm   = (wave >> 2) * 128;
    const int wn   = (wave & 3) * 32;

    const int nwg  = (int)(gridDim.x * gridDim.y);
    const int bid0 = (int)(blockIdx.y * gridDim.x + blockIdx.x);
    const int bid  = (bid0 & 7) * (nwg >> 3) + (bid0 >> 3);
    const int n0   = (bid % (int)gridDim.x) * 128;
    const int m0   = (bid / (int)gridDim.x) * 256;

    const int nt = K >> 6;                // even by contract

    const int csrc = (tid & 3) ^ ((tid >> 4) & 2);
    const u16* Ag   = A   + (long long)(m0 + (tid >> 2)) * K + csrc * 8;
    const u16* Bmug = Wmu + (long long)(n0 + (tid >> 2)) * K + csrc * 8;
    const u16* Blsg = Wls + (long long)(n0 + (tid >> 2)) * K + csrc * 8;
    const long long hstep = 128LL * K;

    const int swz   = (fq * 8) ^ ((fr & 8) << 1);
    const int a_rd  = (wave >> 2) * 8192 + fr * 32 + swz;
    const int bh_rd = ((wave & 3) * 32 + fr) * 32 + swz;

    f32x4 accMu[8][2] = {}, accLs[8][2] = {};
    bf16x8 af[4][2], bfMu[2][2], bfLs[2][2];

    // prologue: tile0 {Bmu,Bls,A-h0,A-h1}, tile1 {Bmu,Bls}; drain tile0.
    STAGE_BH(0, 0, 0);
    STAGE_BH(0, 1, 0);
    STAGE_AH(0, 0, 0);
    STAGE_AH(0, 1, 0);
    STAGE_BH(1, 0, 1);
    STAGE_BH(1, 1, 1);
    asm volatile("s_waitcnt vmcnt(4)" ::: "memory");
    BAR();

    #pragma unroll 1
    for (int kt = 0; kt < nt; kt += 2) {
        TILE_H(0, kt);
        TILE_H(1, kt + 1);
    }

    // fused epilogue: mu, std=exp(0.5*ls), tanh(eps*std+mu) -> zc[:, :1024].
    #pragma unroll
    for (int ni = 0; ni < 2; ++ni) {
        const int col = n0 + wn + ni * 16 + fr;
        const float bmu_v = bmu[col];
        const float bls_v = bls[col];
        #pragma unroll
        for (int mi = 0; mi < 8; ++mi) {
            const int row = m0 + wm + mi * 16 + fq * 4;
            #pragma unroll
            for (int r = 0; r < 4; ++r) {
                const long long idx = (long long)(row + r) * 1024 + col;
                const float muv = accMu[mi][ni][r] + bmu_v;
                const float sdv = expf(0.5f * (accLs[mi][ni][r] + bls_v));
                muO[idx]  = muv;
                stdO[idx] = sdv;
                const float z = eps[idx] * sdv + muv;
                zc[(long long)(row + r) * K_CAT + col] = to_bf16(fast_tanh(z));
            }
        }
    }
}

#undef STAGE_AH
#undef STAGE_BH
#undef LOAD_AFH
#undef LOAD_BH
#undef MMA_H2
#undef TILE_H

// ---------------------------------------------------------------------------
// LayerNorm(z=1024) + tanh -> bf16. One 256-thread block per row.
// ---------------------------------------------------------------------------
__global__ __launch_bounds__(256)
void ln_tanh_kernel(const float* __restrict__ in, const float* __restrict__ g,
                    const float* __restrict__ be, u16* __restrict__ out)
{
    const int row = blockIdx.x;
    const int t = threadIdx.x;
    const float4 v = ((const float4*)(in + (long long)row * 1024))[t];
    float s  = v.x + v.y + v.z + v.w;
    float s2 = v.x * v.x + v.y * v.y + v.z * v.z + v.w * v.w;
    #pragma unroll
    for (int off = 32; off > 0; off >>= 1) {
        s  += __shfl_down(s,  off);
        s2 += __shfl_down(s2, off);
    }
    __shared__ float red[8];
    if ((t & 63) == 0) { red[t >> 6] = s; red[4 + (t >> 6)] = s2; }
    __syncthreads();
    s  = red[0] + red[1] + red[2] + red[3];
    s2 = red[4] + red[5] + red[6] + red[7];
    const float mean = s * (1.0f / 1024.0f);
    const float inv  = rsqrtf(s2 * (1.0f / 1024.0f) - mean * mean + 1e-5f);
    const float4 gg = ((const float4*)g)[t];
    const float4 bb = ((const float4*)be)[t];
    u16x4 o;
    o.x = to_bf16(fast_tanh((v.x - mean) * inv * gg.x + bb.x));
    o.y = to_bf16(fast_tanh((v.y - mean) * inv * gg.y + bb.y));
    o.z = to_bf16(fast_tanh((v.z - mean) * inv * gg.z + bb.z));
    o.w = to_bf16(fast_tanh((v.w - mean) * inv * gg.w + bb.w));
    ((u16x4*)(out + (long long)row * 1024))[t] = o;
}

// ---------------------------------------------------------------------------
// x prep: x fp32 -> x bf16 (GEMM1 A) and tanh(x) bf16 -> zc[:, 1024:5120].
// ---------------------------------------------------------------------------
__global__ __launch_bounds__(256)
void prep_x_kernel(const float* __restrict__ x, u16* __restrict__ xb,
                   u16* __restrict__ zc)
{
    const long long i = (long long)blockIdx.x * 256 + threadIdx.x;  // float4 index
    const float4 v = ((const float4*)x)[i];
    u16x4 b;
    b.x = to_bf16(v.x); b.y = to_bf16(v.y); b.z = to_bf16(v.z); b.w = to_bf16(v.w);
    ((u16x4*)xb)[i] = b;
    const long long flat = i * 4;
    const long long row = flat >> 12;        // / 4096
    const int col = (int)(flat & 4095);
    u16x4 tq;
    tq.x = to_bf16(fast_tanh(v.x)); tq.y = to_bf16(fast_tanh(v.y));
    tq.z = to_bf16(fast_tanh(v.z)); tq.w = to_bf16(fast_tanh(v.w));
    *(u16x4*)(zc + row * (long long)K_CAT + 1024 + col) = tq;
}

// fp32 -> bf16 bulk convert (n4 = count of float4 quads)
__global__ __launch_bounds__(256)
void cvt_kernel(const float* __restrict__ src, u16* __restrict__ dst, long long n4)
{
    const long long i = (long long)blockIdx.x * 256 + threadIdx.x;
    if (i >= n4) return;
    const float4 v = ((const float4*)src)[i];
    u16x4 b;
    b.x = to_bf16(v.x); b.y = to_bf16(v.y); b.z = to_bf16(v.z); b.w = to_bf16(v.w);
    ((u16x4*)dst)[i] = b;
}

// Merged fp32->bf16 convert of the 4 pre-GEMM1 weight tensors.
__global__ __launch_bounds__(256)
void cvt4_kernel(const float* __restrict__ s0, u16* __restrict__ d0,
                 const float* __restrict__ s1, u16* __restrict__ d1,
                 const float* __restrict__ s2, u16* __restrict__ d2,
                 const float* __restrict__ s3, u16* __restrict__ d3)
{
    long long i = (long long)blockIdx.x * 256 + threadIdx.x;
    const float* s; u16* d;
    if (i < 1048576)      { s = s0; d = d0; }
    else if (i < 1310720) { s = s1; d = d1; i -= 1048576; }
    else if (i < 1572864) { s = s2; d = d2; i -= 1310720; }
    else                  { s = s3; d = d3; i -= 1572864; }
    const float4 v = ((const float4*)s)[i];
    u16x4 b;
    b.x = to_bf16(v.x); b.y = to_bf16(v.y); b.z = to_bf16(v.z); b.w = to_bf16(v.w);
    ((u16x4*)d)[i] = b;
}

extern "C" void kernel_launch(void* const* d_in, const int* in_sizes, int n_in,
                              void* d_out, int out_size, void* d_ws, size_t ws_size,
                              hipStream_t stream)
{
    const float* x   = (const float*)d_in[0];
    const float* eps = (const float*)d_in[1];
    const float* W1  = (const float*)d_in[2];
    const float* b1  = (const float*)d_in[3];
    const float* g1  = (const float*)d_in[4];
    const float* be1 = (const float*)d_in[5];
    const float* W2  = (const float*)d_in[6];
    const float* b2  = (const float*)d_in[7];
    const float* g2  = (const float*)d_in[8];
    const float* be2 = (const float*)d_in[9];
    const float* Wmu = (const float*)d_in[10];
    const float* bmu = (const float*)d_in[11];
    const float* Wls = (const float*)d_in[12];
    const float* bls = (const float*)d_in[13];
    const float* Wzw = (const float*)d_in[14];
    const float* bzw = (const float*)d_in[15];

    float* out  = (float*)d_out;                         // [8192,4096]
    float* mu   = out + (long long)M_TOT * D_OUT;        // [8192,1024]
    float* std_ = mu  + (long long)M_TOT * Z_DIM;        // [8192,1024]

    // workspace layout (bytes):
    char* ws = (char*)d_ws;
    u16*   xb   = (u16*)(ws);                  //  67,108,864  x bf16 [8192,4096]
    u16*   zc   = (u16*)(ws +  67108864);      //  83,886,080  concat bf16 [8192,5120]
    u16*   h1   = (u16*)(ws + 150994944);      //  16,777,216
    u16*   h2   = (u16*)(ws + 167772160);      //  16,777,216
    float* pre  = (float*)(ws + 184549376);    //  33,554,432  GEMM fp32 out [8192,1024]
    u16*   W1b  = (u16*)(ws + 218103808);      //   8,388,608
    u16*   W2b  = (u16*)(ws + 226492416);      //   2,097,152
    u16*   Wmub = (u16*)(ws + 228589568);      //   2,097,152
    u16*   Wlsb = (u16*)(ws + 230686720);      //   2,097,152
    u16*   Wzwb = (u16*)(ws);                  // reuses xb region after GEMM1 (42MB<=64MB)
    // total ws = 232,783,872 bytes

    // weight conversions (merged: 1 launch instead of 4)
    cvt4_kernel<<<7168, 256, 0, stream>>>(W1, W1b, W2, W2b, Wmu, Wmub, Wls, Wlsb);

    // x -> bf16 + tanh(x) into concat buffer right half
    prep_x_kernel<<<32768, 256, 0, stream>>>(x, xb, zc);

    // layer 1: pre = x @ W1^T + b1 ; h1 = tanh(LN(pre))
    gemm128n<<<dim3(8, 32, 1), 512, 0, stream>>>(xb, W1b, b1, pre,
                                                 M_TOT, Z_DIM, D_IN);
    ln_tanh_kernel<<<8192, 256, 0, stream>>>(pre, g1, be1, h1);

    // Wzw conversion AFTER gemm1 (Wzwb aliases xb)
    cvt_kernel<<<20480, 256, 0, stream>>>(Wzw, Wzwb, 5242880);

    // layer 2
    gemm128n<<<dim3(8, 32, 1), 512, 0, stream>>>(h1, W2b, b2, pre,
                                                 M_TOT, Z_DIM, Z_DIM);
    ln_tanh_kernel<<<8192, 256, 0, stream>>>(pre, g2, be2, h2);

    // fused mu/logsigma heads + reparameterization: mu, std=exp(0.5*ls),
    // tanh(eps*std+mu) -> zc left half. 256 blocks = 1/CU.
    gemm_heads<<<dim3(8, 32, 1), 512, 0, stream>>>(h2, Wmub, Wlsb, bmu, bls,
                                                   eps, mu, std_, zc, Z_DIM);

    // final projection: out = tanh([z,x]) @ Wzw^T + bzw — the dominant GEMM
    // (343.6 GFLOP), on the verified 8-phase 256^2 schedule.
    gemm256<<<dim3(16, 32, 1), 512, 0, stream>>>(zc, Wzwb, bzw, out,
                                                 M_TOT, D_OUT, K_CAT);
}

// Round 12
// 879.430 us; speedup vs baseline: 1.0493x; 1.0493x over previous
//
#include <hip/hip_runtime.h>
#include <cstdint>

typedef unsigned short u16;
typedef __bf16 bf16x8 __attribute__((ext_vector_type(8)));
typedef float f32x4 __attribute__((ext_vector_type(4)));

#define M_TOT 8192      // B*S
#define D_IN  4096
#define Z_DIM 1024
#define D_OUT 4096
#define K_CAT 5120      // Z + D_IN

struct alignas(8) u16x4 { u16 x, y, z, w; };

__device__ __forceinline__ u16 to_bf16(float f) {
    union { float f; uint32_t u; } v; v.f = f;
    uint32_t u = v.u;
    // round-to-nearest-even
    uint32_t r = (u + 0x7FFFu + ((u >> 16) & 1u)) >> 16;
    return (u16)r;
}

// Fast tanh: 1 - 2/(e^{2x}+1) via v_exp_f32 + v_rcp_f32 (~6 instr vs the
// ~50-100-cycle libm tanhf). Abs error ~1e-6 << bf16 ulp; saturates
// correctly (x>>0: e=inf -> 1; x<<0: e=0 -> -1). Verified (absmax
// unchanged, round 11). Kept; the round-11 gemm_heads fusion is REVERTED
// (regressed +45us — register-ceiling spill signature, invisible below the
// top-5 counter cutoff; rev-4/5 lesson: never add live state to a kernel
// sitting at the 256-reg/wave budget).
__device__ __forceinline__ float fast_tanh(float x) {
    const float e = __expf(2.0f * x);
    return 1.0f - 2.0f * __builtin_amdgcn_rcpf(e + 1.0f);
}

__device__ __forceinline__ void async_load16(const void* g, void* l) {
    __builtin_amdgcn_global_load_lds(
        (const __attribute__((address_space(1))) void*)g,
        (__attribute__((address_space(3))) void*)l,
        16, 0, 0);
}

#define BAR() do { asm volatile("" ::: "memory"); \
                   __builtin_amdgcn_s_barrier(); \
                   asm volatile("" ::: "memory"); } while (0)

// ---------------------------------------------------------------------------
// 256x256-tile 8-phase GEMM — rev-6 schedule, verified best (317us/48.5%/
// 0 conflicts on the final projection). Converged; do not perturb.
//   Geometry: BK=64, 512 thr = 8 waves (2M x 4N), per-wave out 128x64.
//   LDS 128 KiB: 2 dbuf x (A 32KB + B 32KB), XOR swizzle via pre-swizzled
//   GLOBAL source chunk (LDS dest linear: wave-uniform base + lane*16).
//   Staging: p0 A-h0(t+1)->b^1, p1 A-h1(t+1)->b^1, p2 B-h0(t+2)->b,
//   p3 B-h1(t+2)->b; vmcnt(4) before p3's barrier -> tile t+1 fully
//   resident; bf0(t+1) prefetched after the residency barrier (dead regs).
//   Requires: M%256==0, N%256==0, K%128==0, (gridDim.x*gridDim.y)%8==0.
// ---------------------------------------------------------------------------

#define STAGE_A(buf, h, kt_) do { if ((kt_) < nt) {                            \
    const u16* g_ = Ag + (long long)(h) * hstep + ((long long)(kt_) << 6);     \
    async_load16(g_,      &lds16[(buf) * 32768 + (h) * 8192        + wave * 512]); \
    async_load16(g_ + 32, &lds16[(buf) * 32768 + (h) * 8192 + 4096 + wave * 512]); \
  } } while (0)

#define STAGE_B(buf, h, kt_) do { if ((kt_) < nt) {                            \
    const u16* g_ = Bg + (long long)(h) * hstep + ((long long)(kt_) << 6);     \
    async_load16(g_,      &lds16[16384 + (buf) * 32768 + (h) * 8192        + wave * 512]); \
    async_load16(g_ + 32, &lds16[16384 + (buf) * 32768 + (h) * 8192 + 4096 + wave * 512]); \
  } } while (0)

#define LOAD_AF(buf, mbase)                                                    \
    _Pragma("unroll")                                                          \
    for (int mi_ = 0; mi_ < 4; ++mi_) {                                        \
      _Pragma("unroll")                                                        \
      for (int ks_ = 0; ks_ < 2; ++ks_)                                        \
        af[mi_][ks_] = *(const bf16x8*)&lds16[(buf) * 32768 + a_rd             \
                                              + ks_ * 4096 + ((mbase) + mi_) * 512]; \
    }

#define LOAD_B(dst, buf, nbase)                                                \
    _Pragma("unroll")                                                          \
    for (int ni_ = 0; ni_ < 2; ++ni_) {                                        \
      _Pragma("unroll")                                                        \
      for (int ks_ = 0; ks_ < 2; ++ks_)                                        \
        dst[ni_][ks_] = *(const bf16x8*)&lds16[(buf) * 32768 + b_rd            \
                                               + ks_ * 4096 + ((nbase) + ni_) * 512]; \
    }

#define MMA_Q(bfx, mo, no) do {                                                \
    __builtin_amdgcn_s_setprio(1);                                             \
    _Pragma("unroll")                                                          \
    for (int mi_ = 0; mi_ < 4; ++mi_) {                                        \
      _Pragma("unroll")                                                        \
      for (int ni_ = 0; ni_ < 2; ++ni_) {                                      \
        _Pragma("unroll")                                                      \
        for (int ks_ = 0; ks_ < 2; ++ks_)                                      \
          acc[(mo) + mi_][(no) + ni_] = __builtin_amdgcn_mfma_f32_16x16x32_bf16( \
              af[mi_][ks_], bfx[ni_][ks_], acc[(mo) + mi_][(no) + ni_], 0, 0, 0); \
      }                                                                        \
    }                                                                          \
    __builtin_amdgcn_s_setprio(0);                                             \
  } while (0)

#define TILE(b, kt_) do {                                                      \
    LOAD_AF(b, 0);                                                             \
    STAGE_A((b) ^ 1, 0, (kt_) + 1);                                            \
    BAR();                                                                     \
    MMA_Q(bf0, 0, 0);                                                          \
    BAR();                                                                     \
    LOAD_B(bf1, b, 2);                                                         \
    STAGE_A((b) ^ 1, 1, (kt_) + 1);                                            \
    BAR();                                                                     \
    MMA_Q(bf1, 0, 2);                                                          \
    BAR();                                                                     \
    LOAD_AF(b, 4);                                                             \
    STAGE_B(b, 0, (kt_) + 2);                                                  \
    BAR();                                                                     \
    MMA_Q(bf0, 4, 0);                                                          \
    BAR();                                                                     \
    STAGE_B(b, 1, (kt_) + 2);                                                  \
    if ((kt_) + 2 < nt) { asm volatile("s_waitcnt vmcnt(4)" ::: "memory"); }   \
    else                { asm volatile("s_waitcnt vmcnt(0)" ::: "memory"); }   \
    BAR();                                                                     \
    LOAD_B(bf0, (b) ^ 1, 0);                                                   \
    MMA_Q(bf1, 4, 2);                                                          \
    BAR();                                                                     \
  } while (0)

template <bool EXPLS>
__global__ __launch_bounds__(512)
void gemm256(const u16* __restrict__ A,
             const u16* __restrict__ Bw0, const u16* __restrict__ Bw1,
             const float* __restrict__ bias0, const float* __restrict__ bias1,
             float* __restrict__ C0, float* __restrict__ C1,
             int M, int N, int K)
{
    const u16*   Bw   = blockIdx.z ? Bw1   : Bw0;
    const float* bias = blockIdx.z ? bias1 : bias0;
    float*       C    = blockIdx.z ? C1    : C0;

    __shared__ u16 lds16[65536];          // 128 KiB

    const int tid  = threadIdx.x;
    const int wave = tid >> 6;
    const int lane = tid & 63;
    const int fr   = lane & 15;
    const int fq   = lane >> 4;
    const int wm   = (wave >> 2) * 128;   // 2 wave-rows (M)
    const int wn   = (wave & 3) * 64;     // 4 wave-cols (N)

    const int nwg  = (int)(gridDim.x * gridDim.y);
    const int bid0 = (int)(blockIdx.y * gridDim.x + blockIdx.x);
    const int bid  = (bid0 & 7) * (nwg >> 3) + (bid0 >> 3);
    const int n0   = (bid % (int)gridDim.x) * 256;
    const int m0   = (bid / (int)gridDim.x) * 256;

    const int nt = K >> 6;                // # K-tiles (BK=64); even by contract

    const int csrc = (tid & 3) ^ ((tid >> 4) & 2);
    const u16* Ag = A  + (long long)(m0 + (tid >> 2)) * K + csrc * 8;
    const u16* Bg = Bw + (long long)(n0 + (tid >> 2)) * K + csrc * 8;
    const long long hstep = 128LL * K;

    const int swz  = (fq * 8) ^ ((fr & 8) << 1);
    const int a_rd = (wave >> 2) * 8192 + fr * 32 + swz;
    const int b_rd = 16384 + ((wave & 3) >> 1) * 8192
                   + ((wave & 1) * 64 + fr) * 32 + swz;

    f32x4 acc[8][4] = {};
    bf16x8 af[4][2], bf0[2][2], bf1[2][2];

    STAGE_B(0, 0, 0);
    STAGE_B(0, 1, 0);
    STAGE_A(0, 0, 0);
    STAGE_A(0, 1, 0);
    STAGE_B(1, 0, 1);
    STAGE_B(1, 1, 1);
    asm volatile("s_waitcnt vmcnt(4)" ::: "memory");
    BAR();
    LOAD_B(bf0, 0, 0);

    #pragma unroll 1
    for (int kt = 0; kt < nt; kt += 2) {
        TILE(0, kt);
        TILE(1, kt + 1);
    }

    #pragma unroll
    for (int ni = 0; ni < 4; ++ni) {
        const int col = n0 + wn + ni * 16 + fr;
        const float bv = bias[col];
        #pragma unroll
        for (int mi = 0; mi < 8; ++mi) {
            const int row = m0 + wm + mi * 16 + fq * 4;
            float* cp = C + (long long)row * N + col;
            #pragma unroll
            for (int r = 0; r < 4; ++r) {
                float v = acc[mi][ni][r] + bv;
                if constexpr (EXPLS) { if (blockIdx.z) v = expf(0.5f * v); }
                cp[(long long)r * N] = v;
            }
        }
    }
}

#undef STAGE_A
#undef STAGE_B
#undef LOAD_AF
#undef LOAD_B
#undef MMA_Q
#undef TILE

// ---------------------------------------------------------------------------
// 256x128-tile GEMM (gemm128n) — verified (877us total round 10).
// BM=256, BN=128, BK=64; 8 waves; LDS 96KB; 2 phases/K-tile; vmcnt(2).
// ---------------------------------------------------------------------------

#define STAGE_A1(buf, h, kt_) do { if ((kt_) < nt) {                           \
    const u16* g_ = Ag + (long long)(h) * hstep + ((long long)(kt_) << 6);     \
    async_load16(g_,      &lds16[(buf) * 24576 + (h) * 8192        + wave * 512]); \
    async_load16(g_ + 32, &lds16[(buf) * 24576 + (h) * 8192 + 4096 + wave * 512]); \
  } } while (0)

#define STAGE_B1(buf, kt_) do { if ((kt_) < nt) {                              \
    const u16* g_ = Bg + ((long long)(kt_) << 6);                              \
    async_load16(g_,      &lds16[(buf) * 24576 + 16384        + wave * 512]);  \
    async_load16(g_ + 32, &lds16[(buf) * 24576 + 16384 + 4096 + wave * 512]);  \
  } } while (0)

#define LOAD_AF1(buf, mbase)                                                   \
    _Pragma("unroll")                                                          \
    for (int mi_ = 0; mi_ < 4; ++mi_) {                                        \
      _Pragma("unroll")                                                        \
      for (int ks_ = 0; ks_ < 2; ++ks_)                                        \
        af[mi_][ks_] = *(const bf16x8*)&lds16[(buf) * 24576 + a_rd             \
                                              + ks_ * 4096 + ((mbase) + mi_) * 512]; \
    }

#define LOAD_BF1(dst, buf)                                                     \
    _Pragma("unroll")                                                          \
    for (int ni_ = 0; ni_ < 2; ++ni_) {                                        \
      _Pragma("unroll")                                                        \
      for (int ks_ = 0; ks_ < 2; ++ks_)                                        \
        dst[ni_][ks_] = *(const bf16x8*)&lds16[(buf) * 24576 + b_rd            \
                                               + ks_ * 4096 + ni_ * 512];      \
    }

#define MMA_H(bfx, mo) do {                                                    \
    __builtin_amdgcn_s_setprio(1);                                             \
    _Pragma("unroll")                                                          \
    for (int mi_ = 0; mi_ < 4; ++mi_) {                                        \
      _Pragma("unroll")                                                        \
      for (int ni_ = 0; ni_ < 2; ++ni_) {                                      \
        _Pragma("unroll")                                                      \
        for (int ks_ = 0; ks_ < 2; ++ks_)                                      \
          acc[(mo) + mi_][ni_] = __builtin_amdgcn_mfma_f32_16x16x32_bf16(      \
              af[mi_][ks_], bfx[ni_][ks_], acc[(mo) + mi_][ni_], 0, 0, 0);     \
      }                                                                        \
    }                                                                          \
    __builtin_amdgcn_s_setprio(0);                                             \
  } while (0)

#define TILE1(b, kt_, bfCur, bfNxt) do {                                       \
    LOAD_AF1(b, 0);                                                            \
    STAGE_A1((b) ^ 1, 0, (kt_) + 1);                                           \
    BAR();                                                                     \
    MMA_H(bfCur, 0);                                                           \
    BAR();                                                                     \
    LOAD_AF1(b, 4);                                                            \
    STAGE_A1((b) ^ 1, 1, (kt_) + 1);                                           \
    STAGE_B1(b, (kt_) + 2);                                                    \
    if ((kt_) + 2 < nt) { asm volatile("s_waitcnt vmcnt(2)" ::: "memory"); }   \
    else                { asm volatile("s_waitcnt vmcnt(0)" ::: "memory"); }   \
    BAR();                                                                     \
    LOAD_BF1(bfNxt, (b) ^ 1);                                                  \
    MMA_H(bfCur, 4);                                                           \
    BAR();                                                                     \
  } while (0)

__global__ __launch_bounds__(512)
void gemm128n(const u16* __restrict__ A, const u16* __restrict__ Bw,
              const float* __restrict__ bias, float* __restrict__ C,
              int M, int N, int K)
{
    __shared__ u16 lds16[49152];          // 96 KiB

    const int tid  = threadIdx.x;
    const int wave = tid >> 6;
    const int lane = tid & 63;
    const int fr   = lane & 15;
    const int fq   = lane >> 4;
    const int wm   = (wave >> 2) * 128;   // 2 wave-rows (M)
    const int wn   = (wave & 3) * 32;     // 4 wave-cols (N)

    const int nwg  = (int)(gridDim.x * gridDim.y);
    const int bid0 = (int)(blockIdx.y * gridDim.x + blockIdx.x);
    const int bid  = (bid0 & 7) * (nwg >> 3) + (bid0 >> 3);
    const int n0   = (bid % (int)gridDim.x) * 128;
    const int m0   = (bid / (int)gridDim.x) * 256;

    const int nt = K >> 6;                // even by contract (K%128==0)

    const int csrc = (tid & 3) ^ ((tid >> 4) & 2);
    const u16* Ag = A  + (long long)(m0 + (tid >> 2)) * K + csrc * 8;
    const u16* Bg = Bw + (long long)(n0 + (tid >> 2)) * K + csrc * 8;
    const long long hstep = 128LL * K;

    const int swz  = (fq * 8) ^ ((fr & 8) << 1);
    const int a_rd = (wave >> 2) * 8192 + fr * 32 + swz;
    const int b_rd = 16384 + ((wave & 3) * 32 + fr) * 32 + swz;

    f32x4 acc[8][2] = {};
    bf16x8 af[4][2], bfA[2][2], bfB[2][2];

    STAGE_B1(0, 0);
    STAGE_A1(0, 0, 0);
    STAGE_A1(0, 1, 0);
    STAGE_B1(1, 1);
    asm volatile("s_waitcnt vmcnt(2)" ::: "memory");
    BAR();
    LOAD_BF1(bfA, 0);

    #pragma unroll 1
    for (int kt = 0; kt < nt; kt += 2) {
        TILE1(0, kt,     bfA, bfB);
        TILE1(1, kt + 1, bfB, bfA);
    }

    #pragma unroll
    for (int ni = 0; ni < 2; ++ni) {
        const int col = n0 + wn + ni * 16 + fr;
        const float bv = bias[col];
        #pragma unroll
        for (int mi = 0; mi < 8; ++mi) {
            const int row = m0 + wm + mi * 16 + fq * 4;
            float* cp = C + (long long)row * N + col;
            #pragma unroll
            for (int r = 0; r < 4; ++r)
                cp[(long long)r * N] = acc[mi][ni][r] + bv;
        }
    }
}

#undef STAGE_A1
#undef STAGE_B1
#undef LOAD_AF1
#undef LOAD_BF1
#undef MMA_H
#undef TILE1

// ---------------------------------------------------------------------------
// LayerNorm(z=1024) + tanh -> bf16. One 256-thread block per row.
// ---------------------------------------------------------------------------
__global__ __launch_bounds__(256)
void ln_tanh_kernel(const float* __restrict__ in, const float* __restrict__ g,
                    const float* __restrict__ be, u16* __restrict__ out)
{
    const int row = blockIdx.x;
    const int t = threadIdx.x;
    const float4 v = ((const float4*)(in + (long long)row * 1024))[t];
    float s  = v.x + v.y + v.z + v.w;
    float s2 = v.x * v.x + v.y * v.y + v.z * v.z + v.w * v.w;
    #pragma unroll
    for (int off = 32; off > 0; off >>= 1) {
        s  += __shfl_down(s,  off);
        s2 += __shfl_down(s2, off);
    }
    __shared__ float red[8];
    if ((t & 63) == 0) { red[t >> 6] = s; red[4 + (t >> 6)] = s2; }
    __syncthreads();
    s  = red[0] + red[1] + red[2] + red[3];
    s2 = red[4] + red[5] + red[6] + red[7];
    const float mean = s * (1.0f / 1024.0f);
    const float inv  = rsqrtf(s2 * (1.0f / 1024.0f) - mean * mean + 1e-5f);
    const float4 gg = ((const float4*)g)[t];
    const float4 bb = ((const float4*)be)[t];
    u16x4 o;
    o.x = to_bf16(fast_tanh((v.x - mean) * inv * gg.x + bb.x));
    o.y = to_bf16(fast_tanh((v.y - mean) * inv * gg.y + bb.y));
    o.z = to_bf16(fast_tanh((v.z - mean) * inv * gg.z + bb.z));
    o.w = to_bf16(fast_tanh((v.w - mean) * inv * gg.w + bb.w));
    ((u16x4*)(out + (long long)row * 1024))[t] = o;
}

// ---------------------------------------------------------------------------
// x prep: x fp32 -> x bf16 (GEMM1 A) and tanh(x) bf16 -> zc[:, 1024:5120].
// ---------------------------------------------------------------------------
__global__ __launch_bounds__(256)
void prep_x_kernel(const float* __restrict__ x, u16* __restrict__ xb,
                   u16* __restrict__ zc)
{
    const long long i = (long long)blockIdx.x * 256 + threadIdx.x;  // float4 index
    const float4 v = ((const float4*)x)[i];
    u16x4 b;
    b.x = to_bf16(v.x); b.y = to_bf16(v.y); b.z = to_bf16(v.z); b.w = to_bf16(v.w);
    ((u16x4*)xb)[i] = b;
    const long long flat = i * 4;
    const long long row = flat >> 12;        // / 4096
    const int col = (int)(flat & 4095);
    u16x4 tq;
    tq.x = to_bf16(fast_tanh(v.x)); tq.y = to_bf16(fast_tanh(v.y));
    tq.z = to_bf16(fast_tanh(v.z)); tq.w = to_bf16(fast_tanh(v.w));
    *(u16x4*)(zc + row * (long long)K_CAT + 1024 + col) = tq;
}

// ---------------------------------------------------------------------------
// Reparameterization: std was already computed by the ls-head GEMM epilogue
// (exp fused). Here: z = eps*std + mu, tanh(z) bf16 -> zc[:, 0:1024].
// ---------------------------------------------------------------------------
__global__ __launch_bounds__(256)
void reparam_kernel(const float* __restrict__ mu, const float* __restrict__ stdv,
                    const float* __restrict__ eps, u16* __restrict__ zc)
{
    const long long row = blockIdx.x;
    const int c = threadIdx.x * 4;
    const long long idx = row * 1024 + c;
    const float4 m = *(const float4*)(mu + idx);
    const float4 sd = *(const float4*)(stdv + idx);
    const float4 e = *(const float4*)(eps + idx);
    u16x4 t;
    t.x = to_bf16(fast_tanh(e.x * sd.x + m.x));
    t.y = to_bf16(fast_tanh(e.y * sd.y + m.y));
    t.z = to_bf16(fast_tanh(e.z * sd.z + m.z));
    t.w = to_bf16(fast_tanh(e.w * sd.w + m.w));
    *(u16x4*)(zc + row * (long long)K_CAT + c) = t;
}

// fp32 -> bf16 bulk convert (n4 = count of float4 quads)
__global__ __launch_bounds__(256)
void cvt_kernel(const float* __restrict__ src, u16* __restrict__ dst, long long n4)
{
    const long long i = (long long)blockIdx.x * 256 + threadIdx.x;
    if (i >= n4) return;
    const float4 v = ((const float4*)src)[i];
    u16x4 b;
    b.x = to_bf16(v.x); b.y = to_bf16(v.y); b.z = to_bf16(v.z); b.w = to_bf16(v.w);
    ((u16x4*)dst)[i] = b;
}

// Merged fp32->bf16 convert of the 4 pre-GEMM1 weight tensors.
__global__ __launch_bounds__(256)
void cvt4_kernel(const float* __restrict__ s0, u16* __restrict__ d0,
                 const float* __restrict__ s1, u16* __restrict__ d1,
                 const float* __restrict__ s2, u16* __restrict__ d2,
                 const float* __restrict__ s3, u16* __restrict__ d3)
{
    long long i = (long long)blockIdx.x * 256 + threadIdx.x;
    const float* s; u16* d;
    if (i < 1048576)      { s = s0; d = d0; }
    else if (i < 1310720) { s = s1; d = d1; i -= 1048576; }
    else if (i < 1572864) { s = s2; d = d2; i -= 1310720; }
    else                  { s = s3; d = d3; i -= 1572864; }
    const float4 v = ((const float4*)s)[i];
    u16x4 b;
    b.x = to_bf16(v.x); b.y = to_bf16(v.y); b.z = to_bf16(v.z); b.w = to_bf16(v.w);
    ((u16x4*)d)[i] = b;
}

extern "C" void kernel_launch(void* const* d_in, const int* in_sizes, int n_in,
                              void* d_out, int out_size, void* d_ws, size_t ws_size,
                              hipStream_t stream)
{
    const float* x   = (const float*)d_in[0];
    const float* eps = (const float*)d_in[1];
    const float* W1  = (const float*)d_in[2];
    const float* b1  = (const float*)d_in[3];
    const float* g1  = (const float*)d_in[4];
    const float* be1 = (const float*)d_in[5];
    const float* W2  = (const float*)d_in[6];
    const float* b2  = (const float*)d_in[7];
    const float* g2  = (const float*)d_in[8];
    const float* be2 = (const float*)d_in[9];
    const float* Wmu = (const float*)d_in[10];
    const float* bmu = (const float*)d_in[11];
    const float* Wls = (const float*)d_in[12];
    const float* bls = (const float*)d_in[13];
    const float* Wzw = (const float*)d_in[14];
    const float* bzw = (const float*)d_in[15];

    float* out  = (float*)d_out;                         // [8192,4096]
    float* mu   = out + (long long)M_TOT * D_OUT;        // [8192,1024]
    float* std_ = mu  + (long long)M_TOT * Z_DIM;        // [8192,1024]

    // workspace layout (bytes):
    char* ws = (char*)d_ws;
    u16*   xb   = (u16*)(ws);                  //  67,108,864  x bf16 [8192,4096]
    u16*   zc   = (u16*)(ws +  67108864);      //  83,886,080  concat bf16 [8192,5120]
    u16*   h1   = (u16*)(ws + 150994944);      //  16,777,216
    u16*   h2   = (u16*)(ws + 167772160);      //  16,777,216
    float* pre  = (float*)(ws + 184549376);    //  33,554,432  GEMM fp32 out [8192,1024]
    u16*   W1b  = (u16*)(ws + 218103808);      //   8,388,608
    u16*   W2b  = (u16*)(ws + 226492416);      //   2,097,152
    u16*   Wmub = (u16*)(ws + 228589568);      //   2,097,152
    u16*   Wlsb = (u16*)(ws + 230686720);      //   2,097,152
    u16*   Wzwb = (u16*)(ws);                  // reuses xb region after GEMM1 (42MB<=64MB)
    // total ws = 232,783,872 bytes

    // weight conversions (merged: 1 launch instead of 4)
    cvt4_kernel<<<7168, 256, 0, stream>>>(W1, W1b, W2, W2b, Wmu, Wmub, Wls, Wlsb);

    // x -> bf16 + tanh(x) into concat buffer right half
    prep_x_kernel<<<32768, 256, 0, stream>>>(x, xb, zc);

    // layer 1: pre = x @ W1^T + b1 ; h1 = tanh(LN(pre))
    gemm128n<<<dim3(8, 32, 1), 512, 0, stream>>>(xb, W1b, b1, pre,
                                                 M_TOT, Z_DIM, D_IN);
    ln_tanh_kernel<<<8192, 256, 0, stream>>>(pre, g1, be1, h1);

    // Wzw conversion AFTER gemm1 (Wzwb aliases xb)
    cvt_kernel<<<20480, 256, 0, stream>>>(Wzw, Wzwb, 5242880);

    // layer 2
    gemm128n<<<dim3(8, 32, 1), 512, 0, stream>>>(h1, W2b, b2, pre,
                                                 M_TOT, Z_DIM, Z_DIM);
    ln_tanh_kernel<<<8192, 256, 0, stream>>>(pre, g2, be2, h2);

    // mu / logsigma heads (dual GEMM via gridDim.z) — verified 256^2 kernel,
    // 256 blocks = full chip. EXPLS=true: the z=1 (ls) epilogue writes
    // std = exp(0.5*(acc+bias)) directly into the std_ output slot.
    gemm256<true><<<dim3(4, 32, 2), 512, 0, stream>>>(h2, Wmub, Wlsb, bmu, bls,
                                                      mu, std_,
                                                      M_TOT, Z_DIM, Z_DIM);

    // reparameterize: tanh(eps*std + mu) -> concat left half
    reparam_kernel<<<8192, 256, 0, stream>>>(mu, std_, eps, zc);

    // final projection: out = tanh([z,x]) @ Wzw^T + bzw — the dominant GEMM
    // (343.6 GFLOP), on the verified 8-phase 256^2 schedule.
    gemm256<false><<<dim3(16, 32, 1), 512, 0, stream>>>(zc, Wzwb, Wzwb, bzw, bzw,
                                                        out, out,
                                                        M_TOT, D_OUT, K_CAT);
}